// Round 8
// baseline (137.194 us; speedup 1.0000x reference)
//
#include <hip/hip_runtime.h>

#define NT 512
#define TW 32
#define TH 32
#define IH (TH + 10)   // 42 h-pass rows
#define HP 32          // LDS row stride in elements (swz handles banks)
#define IMW 512
#define IMH 512
#define NBLK ((IMW / TW) * (IMH / TH) * 16)   // 4096 blocks

// native 2-wide fp32 vector -> v_pk_fma_f32 / v_pk_mul_f32 on gfx950
typedef float f32x2 __attribute__((ext_vector_type(2)));
typedef __fp16 fp16x2 __attribute__((ext_vector_type(2)));   // matches cvt_pkrtz return type

__device__ __forceinline__ float wave_reduce(float v) {
    #pragma unroll
    for (int off = 32; off > 0; off >>= 1)
        v += __shfl_down(v, off, 64);
    return v;
}

// LDS column swizzle (verified at HP=32 f32: SQ_LDS_BANK_CONFLICT == 0).
// Bijective on 0..31.
__device__ __forceinline__ int swz(int i) { return i ^ (i >> 3); }

// pack 2 f32 -> 2 f16 (RTZ). Bias analysis: half-ulp truncation ~5e-4 rel on
// 2nd moments -> <=1e-5 on the final scalar; budget 1.98e-2. (R5-verified.)
__device__ __forceinline__ unsigned int pk_f16(f32x2 v) {
    union { fp16x2 h; unsigned int u; } c;
    c.h = __builtin_amdgcn_cvt_pkrtz(v.x, v.y);
    return c.u;
}
__device__ __forceinline__ f32x2 up_f16(unsigned int u) {
    union { unsigned int u; fp16x2 h; } c{u};
    return (f32x2){(float)c.h.x, (float)c.h.y};
}

// Gaussian 1-D weights for ws=11, sigma=1.5 (separable outer product == ref 2-D kernel)
#define G0 0.00102838f
#define G1 0.00759840f
#define G2 0.03600077f
#define G3 0.10936070f
#define G4 0.21300590f
#define G5 0.26601190f

// Horizontal pass over RAW values (transform folded into the epilogue):
// OOB raw fill = -1.0. Identities (exact, incl. borders, since pad -1 maps to
// transformed 0): mu_p=(Mf+1)/2, s_p=(Mff-Mf^2)/4, s_pa=(Mfa-Mf*Ma)/4, etc.
// LDS: h4a=(f,a,b,bb) f32 ; hb=(ff,aa | fa,fb) packed f16. (R5-verified path.)
template<bool BORDER>
__device__ __forceinline__ void h_pass(
    const float* __restrict__ Fp, const float* __restrict__ Ap,
    const float* __restrict__ Bp, int x0, int y0, int tid,
    float4* __restrict__ h4a, uint2* __restrict__ hb)
{
    const float g[11] = {G0, G1, G2, G3, G4, G5, G4, G3, G2, G1, G0};
    if (tid >= IH * 8) return;          // 336 of 512 threads h-active
    const int r  = tid >> 3;
    const int cg = tid & 7;
    const int gy = y0 + r - 5;
    bool yok = true;
    if (BORDER) yok = (gy >= 0) && (gy < IMH);

    f32x2 accs[4][4];
    #pragma unroll
    for (int k = 0; k < 4; ++k)
        #pragma unroll
        for (int q = 0; q < 4; ++q) accs[k][q] = (f32x2){0.f, 0.f};

    // hoisted row bases: 5 loads/image fold to one address + imm offsets
    const int xbase = x0 + 4 * cg - 8;
    const size_t rowo = (size_t)gy * (IMW / 4) + (xbase >> 2);
    const float4* F4 = (const float4*)Fp + rowo;
    const float4* A4 = (const float4*)Ap + rowo;
    const float4* B4 = (const float4*)Bp + rowo;

    #pragma unroll
    for (int w = 0; w < 5; ++w) {
        float4 p4 = {-1.f, -1.f, -1.f, -1.f};
        float4 a4 = {-1.f, -1.f, -1.f, -1.f};
        float4 b4 = {-1.f, -1.f, -1.f, -1.f};
        bool ld = true;
        if (BORDER) {
            const int xc = xbase + 4 * w;
            ld = yok && (xc >= 0) && (xc < IMW);
        }
        if (ld) {
            p4 = F4[w];
            a4 = A4[w];
            b4 = B4[w];
        }
        const float pe[4] = {p4.x, p4.y, p4.z, p4.w};
        const float ae[4] = {a4.x, a4.y, a4.z, a4.w};
        const float be[4] = {b4.x, b4.y, b4.z, b4.w};
        #pragma unroll
        for (int e = 0; e < 4; ++e) {
            const int i = 4 * w + e;
            if (i < 3 || i >= 17) continue;        // unused alignment slack
            const int t = i - 3;                   // window position 0..13
            const float p = pe[e];                 // RAW (no transform)
            const float a = ae[e];
            const float b = be[e];
            const f32x2 v_pa   = {p, a};
            const f32x2 v_ab   = {a, b};
            const f32x2 v_pp2  = {p, p};
            const f32x2 v_ppaa = v_pa * v_pa;      // {ff, aa} v_pk_mul_f32
            const f32x2 v_papb = v_pp2 * v_ab;     // {fa, fb} v_pk_mul_f32
            const f32x2 v_bbb  = {b, b * b};       // {b, bb}
            #pragma unroll
            for (int k = 0; k < 4; ++k) {
                const int j = t - k;               // tap index
                if (j < 0 || j > 10) continue;
                const f32x2 w2 = {g[j], g[j]};
                accs[k][0] += w2 * v_pa;           // v_pk_fma_f32
                accs[k][1] += w2 * v_bbb;
                accs[k][2] += w2 * v_ppaa;
                accs[k][3] += w2 * v_papb;
            }
        }
    }
    #pragma unroll
    for (int k = 0; k < 4; ++k) {
        const int sc = swz(4 * cg + k);
        h4a[r * HP + sc] = make_float4(accs[k][0].x, accs[k][0].y,
                                       accs[k][1].x, accs[k][1].y);
        hb[r * HP + sc]  = make_uint2(pk_f16(accs[k][2]), pk_f16(accs[k][3]));
    }
}

// R8: (1) single-kernel -- per-block atomicAdd to out replaces the finalize
// launch (saves ~10 us of launch overhead; out = 1 - sum*2^-24; per-block
// contribution 2^-12 - blocksum*2^-24, both constants exact in fp32; relies
// on d_out re-init each iter: 0xAA poison as f32 = -3e-13 ~ 0).
// (2) v-pass K=4: 256 active threads x 4 rows -- LDS reads 12 -> 7 insts/px
// (issue-bound regime per R2/R5/R7 occupancy-insensitivity evidence).
// LDS 32.3 KB -> 4 blocks/CU; (512,4) = VGPR cap 128, no spill (R5-proven).
__global__ __launch_bounds__(NT, 4) void ssim_main_kernel(
    const float* __restrict__ fused,
    const float* __restrict__ img_a,
    const float* __restrict__ img_b,
    float* __restrict__ out)
{
    __shared__ float4 h4a[IH * HP];      // (f,a,b,bb) f32
    __shared__ uint2  hb[IH * HP];       // (ff,aa | fa,fb) f16-packed
    __shared__ float red[NT / 64];

    const float g[11] = {G0, G1, G2, G3, G4, G5, G4, G3, G2, G1, G0};

    const int tid = threadIdx.x;
    const int x0 = blockIdx.x * TW;
    const int y0 = blockIdx.y * TH;
    const size_t ioff = (size_t)blockIdx.z * IMW * IMH;
    const float* Fp = fused + ioff;
    const float* Ap = img_a + ioff;
    const float* Bp = img_b + ioff;

    const bool border = (blockIdx.x == 0) | (blockIdx.x == gridDim.x - 1) |
                        (blockIdx.y == 0) | (blockIdx.y == gridDim.y - 1);
    if (border) h_pass<true >(Fp, Ap, Bp, x0, y0, tid, h4a, hb);
    else        h_pass<false>(Fp, Ap, Bp, x0, y0, tid, h4a, hb);
    __syncthreads();

    // -------- vertical pass + SSIM: 256 threads x 4 consecutive rows --------
    const float C1v = 1e-4f;
    const float C2v = 9e-4f;
    float lsum = 0.f;
    if (tid < 256) {
        const int c  = tid & 31;
        const int rg = tid >> 5;          // 0..7
        const int R0 = rg * 4;
        const int sc = swz(c);

        f32x2 m2[4][4];
        #pragma unroll
        for (int k = 0; k < 4; ++k)
            #pragma unroll
            for (int q = 0; q < 4; ++q) m2[k][q] = (f32x2){0.f, 0.f};

        #pragma unroll
        for (int j = 0; j < 14; ++j) {           // rows R0 .. R0+13 (<= 41)
            const float4 va = h4a[(R0 + j) * HP + sc];
            const uint2  vb = hb[(R0 + j) * HP + sc];
            const f32x2 va01 = {va.x, va.y};
            const f32x2 va23 = {va.z, va.w};
            const f32x2 vb01 = up_f16(vb.x);     // {ff, aa}
            const f32x2 vb23 = up_f16(vb.y);     // {fa, fb}
            #pragma unroll
            for (int k = 0; k < 4; ++k) {
                const int t = j - k;                 // tap index
                if (t < 0 || t > 10) continue;
                const f32x2 w2 = {g[t], g[t]};
                m2[k][0] += w2 * va01;               // v_pk_fma_f32
                m2[k][1] += w2 * va23;
                m2[k][2] += w2 * vb01;
                m2[k][3] += w2 * vb23;
            }
        }
        #pragma unroll
        for (int k = 0; k < 4; ++k) {
            // raw moments
            const float Mf  = m2[k][0].x, Ma  = m2[k][0].y;
            const float Mb  = m2[k][1].x, Mbb = m2[k][1].y;
            const float Mff = m2[k][2].x, Maa = m2[k][2].y;
            const float Mfa = m2[k][3].x, Mfb = m2[k][3].y;
            // transformed-domain reconstruction (exact; see h_pass comment):
            // s_p = (Mff - Mf^2)/4, s_pa = (Mfa - Mf*Ma)/4
            // 2*mu_p*mu_a = (Mf+1)(Ma+1)/2 ; mu_p^2+mu_a^2 = ((Mf+1)^2+(Ma+1)^2)/4
            const float Fo = Mf + 1.f;
            const float Ao = Ma + 1.f;
            const float Bo = Mb + 1.f;
            const float sp  = fmaf(-Mf, Mf, Mff) * 0.25f;
            const float sa  = fmaf(-Ma, Ma, Maa) * 0.25f;
            const float sb  = fmaf(-Mb, Mb, Mbb) * 0.25f;
            const float spa = fmaf(-Mf, Ma, Mfa) * 0.25f;
            const float spb = fmaf(-Mf, Mb, Mfb) * 0.25f;
            const float Fo2 = Fo * Fo;
            const float na = fmaf(0.5f * Fo, Ao, C1v) * fmaf(2.f, spa, C2v);
            const float da = fmaf(0.25f, fmaf(Ao, Ao, Fo2), C1v) * (sp + sa + C2v);
            const float nb = fmaf(0.5f * Fo, Bo, C1v) * fmaf(2.f, spb, C2v);
            const float db = fmaf(0.25f, fmaf(Bo, Bo, Fo2), C1v) * (sp + sb + C2v);
            // v_rcp_f32 (~1 ulp) instead of divide; budget 1.98e-2 >> 1e-6
            lsum += na * __builtin_amdgcn_rcpf(da)
                  + nb * __builtin_amdgcn_rcpf(db);
        }
    }

    // ---- block reduction -> ONE device-scope atomicAdd per block -----------
    lsum = wave_reduce(lsum);
    if ((tid & 63) == 0) red[tid >> 6] = lsum;
    __syncthreads();
    if (tid == 0) {
        float s = 0.f;
        #pragma unroll
        for (int i = 0; i < NT / 64; ++i) s += red[i];
        // out = 1 - total*2^-24 ; per block: 1/4096 - s*2^-24 (both exact fp32)
        atomicAdd(out, 0.000244140625f - s * 5.9604644775390625e-8f);
    }
}

extern "C" void kernel_launch(void* const* d_in, const int* in_sizes, int n_in,
                              void* d_out, int out_size, void* d_ws, size_t ws_size,
                              hipStream_t stream) {
    const float* fused = (const float*)d_in[0];
    const float* img_a = (const float*)d_in[1];
    const float* img_b = (const float*)d_in[2];
    float* out = (float*)d_out;
    (void)d_ws; (void)ws_size;

    dim3 grid(IMW / TW, IMH / TH, 16);
    ssim_main_kernel<<<grid, NT, 0, stream>>>(fused, img_a, img_b, out);
}

// Round 9
// 110.753 us; speedup vs baseline: 1.2387x; 1.2387x over previous
//
#include <hip/hip_runtime.h>

#define NT 512
#define TW 32
#define TH 32
#define IH (TH + 10)   // 42 h-pass rows
#define HP 32          // LDS row stride in elements (swz handles banks)
#define IMW 512
#define IMH 512
#define NBLK ((IMW / TW) * (IMH / TH) * 16)   // 4096 partial slots

// native 2-wide fp32 vector -> v_pk_fma_f32 / v_pk_mul_f32 on gfx950
typedef float f32x2 __attribute__((ext_vector_type(2)));
typedef __fp16 fp16x2 __attribute__((ext_vector_type(2)));   // matches cvt_pkrtz return type

__device__ __forceinline__ float wave_reduce(float v) {
    #pragma unroll
    for (int off = 32; off > 0; off >>= 1)
        v += __shfl_down(v, off, 64);
    return v;
}

// LDS column swizzle (verified at HP=32 f32: SQ_LDS_BANK_CONFLICT == 0).
// Bijective on 0..31.
__device__ __forceinline__ int swz(int i) { return i ^ (i >> 3); }

// pack 2 f32 -> 2 f16 (RTZ). Bias analysis: half-ulp truncation ~5e-4 rel on
// 2nd moments -> <=1e-5 on the final scalar; budget 1.98e-2. (R5-verified.)
__device__ __forceinline__ unsigned int pk_f16(f32x2 v) {
    union { fp16x2 h; unsigned int u; } c;
    c.h = __builtin_amdgcn_cvt_pkrtz(v.x, v.y);
    return c.u;
}
__device__ __forceinline__ f32x2 up_f16(unsigned int u) {
    union { unsigned int u; fp16x2 h; } c{u};
    return (f32x2){(float)c.h.x, (float)c.h.y};
}

// Gaussian 1-D weights for ws=11, sigma=1.5 (separable outer product == ref 2-D kernel)
#define G0 0.00102838f
#define G1 0.00759840f
#define G2 0.03600077f
#define G3 0.10936070f
#define G4 0.21300590f
#define G5 0.26601190f

// Horizontal pass over RAW values (transform folded into the epilogue):
// OOB raw fill = -1.0. Identities (exact, incl. borders, since pad -1 maps to
// transformed 0): mu_p=(Mf+1)/2, s_p=(Mff-Mf^2)/4, s_pa=(Mfa-Mf*Ma)/4, etc.
// LDS: h4a=(f,a,b,bb) f32 ; hb=(ff,aa | fa,fb) packed f16. (R5-verified path.)
template<bool BORDER>
__device__ __forceinline__ void h_pass(
    const float* __restrict__ Fp, const float* __restrict__ Ap,
    const float* __restrict__ Bp, int x0, int y0, int tid,
    float4* __restrict__ h4a, uint2* __restrict__ hb)
{
    const float g[11] = {G0, G1, G2, G3, G4, G5, G4, G3, G2, G1, G0};
    if (tid >= IH * 8) return;          // 336 of 512 threads h-active
    const int r  = tid >> 3;
    const int cg = tid & 7;
    const int gy = y0 + r - 5;
    bool yok = true;
    if (BORDER) yok = (gy >= 0) && (gy < IMH);

    f32x2 accs[4][4];
    #pragma unroll
    for (int k = 0; k < 4; ++k)
        #pragma unroll
        for (int q = 0; q < 4; ++q) accs[k][q] = (f32x2){0.f, 0.f};

    // hoisted row bases: 5 loads/image fold to one address + imm offsets
    const int xbase = x0 + 4 * cg - 8;
    const size_t rowo = (size_t)gy * (IMW / 4) + (xbase >> 2);
    const float4* F4 = (const float4*)Fp + rowo;
    const float4* A4 = (const float4*)Ap + rowo;
    const float4* B4 = (const float4*)Bp + rowo;

    #pragma unroll
    for (int w = 0; w < 5; ++w) {
        float4 p4 = {-1.f, -1.f, -1.f, -1.f};
        float4 a4 = {-1.f, -1.f, -1.f, -1.f};
        float4 b4 = {-1.f, -1.f, -1.f, -1.f};
        bool ld = true;
        if (BORDER) {
            const int xc = xbase + 4 * w;
            ld = yok && (xc >= 0) && (xc < IMW);
        }
        if (ld) {
            p4 = F4[w];
            a4 = A4[w];
            b4 = B4[w];
        }
        const float pe[4] = {p4.x, p4.y, p4.z, p4.w};
        const float ae[4] = {a4.x, a4.y, a4.z, a4.w};
        const float be[4] = {b4.x, b4.y, b4.z, b4.w};
        #pragma unroll
        for (int e = 0; e < 4; ++e) {
            const int i = 4 * w + e;
            if (i < 3 || i >= 17) continue;        // unused alignment slack
            const int t = i - 3;                   // window position 0..13
            const float p = pe[e];                 // RAW (no transform)
            const float a = ae[e];
            const float b = be[e];
            const f32x2 v_pa   = {p, a};
            const f32x2 v_ab   = {a, b};
            const f32x2 v_pp2  = {p, p};
            const f32x2 v_ppaa = v_pa * v_pa;      // {ff, aa} v_pk_mul_f32
            const f32x2 v_papb = v_pp2 * v_ab;     // {fa, fb} v_pk_mul_f32
            const f32x2 v_bbb  = {b, b * b};       // {b, bb}
            #pragma unroll
            for (int k = 0; k < 4; ++k) {
                const int j = t - k;               // tap index
                if (j < 0 || j > 10) continue;
                const f32x2 w2 = {g[j], g[j]};
                accs[k][0] += w2 * v_pa;           // v_pk_fma_f32
                accs[k][1] += w2 * v_bbb;
                accs[k][2] += w2 * v_ppaa;
                accs[k][3] += w2 * v_papb;
            }
        }
    }
    #pragma unroll
    for (int k = 0; k < 4; ++k) {
        const int sc = swz(4 * cg + k);
        h4a[r * HP + sc] = make_float4(accs[k][0].x, accs[k][0].y,
                                       accs[k][1].x, accs[k][1].y);
        hb[r * HP + sc]  = make_uint2(pk_f16(accs[k][2]), pk_f16(accs[k][3]));
    }
}

// R9 = R5 structure (best verified 110.8: two kernels, slot stores, f16 2nd
// moments, LDS 32.3 KB -> 4 blocks/CU, (512,4) no-spill) + R8's K=4 v-pass
// (256 threads x 4 rows: v-phase LDS reads 192 -> 112 wave-insts/block,
// same FMA total -- issue-bound regime per R2/R5/R7). R8's atomic exit is
// REVERTED: 4096 same-address RMWs serialized retirement (+26 us).
__global__ __launch_bounds__(NT, 4) void ssim_main_kernel(
    const float* __restrict__ fused,
    const float* __restrict__ img_a,
    const float* __restrict__ img_b,
    float* __restrict__ slots)           // NBLK per-block partials (plain stores)
{
    __shared__ float4 h4a[IH * HP];      // (f,a,b,bb) f32
    __shared__ uint2  hb[IH * HP];       // (ff,aa | fa,fb) f16-packed
    __shared__ float red[NT / 64];

    const float g[11] = {G0, G1, G2, G3, G4, G5, G4, G3, G2, G1, G0};

    const int tid = threadIdx.x;
    const int x0 = blockIdx.x * TW;
    const int y0 = blockIdx.y * TH;
    const size_t ioff = (size_t)blockIdx.z * IMW * IMH;
    const float* Fp = fused + ioff;
    const float* Ap = img_a + ioff;
    const float* Bp = img_b + ioff;

    const bool border = (blockIdx.x == 0) | (blockIdx.x == gridDim.x - 1) |
                        (blockIdx.y == 0) | (blockIdx.y == gridDim.y - 1);
    if (border) h_pass<true >(Fp, Ap, Bp, x0, y0, tid, h4a, hb);
    else        h_pass<false>(Fp, Ap, Bp, x0, y0, tid, h4a, hb);
    __syncthreads();

    // -------- vertical pass + SSIM: 256 threads x 4 consecutive rows --------
    const float C1v = 1e-4f;
    const float C2v = 9e-4f;
    float lsum = 0.f;
    if (tid < 256) {
        const int c  = tid & 31;
        const int rg = tid >> 5;          // 0..7
        const int R0 = rg * 4;
        const int sc = swz(c);

        f32x2 m2[4][4];
        #pragma unroll
        for (int k = 0; k < 4; ++k)
            #pragma unroll
            for (int q = 0; q < 4; ++q) m2[k][q] = (f32x2){0.f, 0.f};

        #pragma unroll
        for (int j = 0; j < 14; ++j) {           // rows R0 .. R0+13 (<= 41)
            const float4 va = h4a[(R0 + j) * HP + sc];
            const uint2  vb = hb[(R0 + j) * HP + sc];
            const f32x2 va01 = {va.x, va.y};
            const f32x2 va23 = {va.z, va.w};
            const f32x2 vb01 = up_f16(vb.x);     // {ff, aa}
            const f32x2 vb23 = up_f16(vb.y);     // {fa, fb}
            #pragma unroll
            for (int k = 0; k < 4; ++k) {
                const int t = j - k;                 // tap index
                if (t < 0 || t > 10) continue;
                const f32x2 w2 = {g[t], g[t]};
                m2[k][0] += w2 * va01;               // v_pk_fma_f32
                m2[k][1] += w2 * va23;
                m2[k][2] += w2 * vb01;
                m2[k][3] += w2 * vb23;
            }
        }
        #pragma unroll
        for (int k = 0; k < 4; ++k) {
            // raw moments
            const float Mf  = m2[k][0].x, Ma  = m2[k][0].y;
            const float Mb  = m2[k][1].x, Mbb = m2[k][1].y;
            const float Mff = m2[k][2].x, Maa = m2[k][2].y;
            const float Mfa = m2[k][3].x, Mfb = m2[k][3].y;
            // transformed-domain reconstruction (exact; see h_pass comment):
            // s_p = (Mff - Mf^2)/4, s_pa = (Mfa - Mf*Ma)/4
            // 2*mu_p*mu_a = (Mf+1)(Ma+1)/2 ; mu_p^2+mu_a^2 = ((Mf+1)^2+(Ma+1)^2)/4
            const float Fo = Mf + 1.f;
            const float Ao = Ma + 1.f;
            const float Bo = Mb + 1.f;
            const float sp  = fmaf(-Mf, Mf, Mff) * 0.25f;
            const float sa  = fmaf(-Ma, Ma, Maa) * 0.25f;
            const float sb  = fmaf(-Mb, Mb, Mbb) * 0.25f;
            const float spa = fmaf(-Mf, Ma, Mfa) * 0.25f;
            const float spb = fmaf(-Mf, Mb, Mfb) * 0.25f;
            const float Fo2 = Fo * Fo;
            const float na = fmaf(0.5f * Fo, Ao, C1v) * fmaf(2.f, spa, C2v);
            const float da = fmaf(0.25f, fmaf(Ao, Ao, Fo2), C1v) * (sp + sa + C2v);
            const float nb = fmaf(0.5f * Fo, Bo, C1v) * fmaf(2.f, spb, C2v);
            const float db = fmaf(0.25f, fmaf(Bo, Bo, Fo2), C1v) * (sp + sb + C2v);
            // v_rcp_f32 (~1 ulp) instead of divide; budget 1.98e-2 >> 1e-6
            lsum += na * __builtin_amdgcn_rcpf(da)
                  + nb * __builtin_amdgcn_rcpf(db);
        }
    }

    // ------- block reduction -> ONE PLAIN STORE per block (no atomics, ------
    // no memset: stores overwrite the 0xAA-poisoned workspace).
    lsum = wave_reduce(lsum);
    if ((tid & 63) == 0) red[tid >> 6] = lsum;
    __syncthreads();
    if (tid == 0) {
        float s = 0.f;
        #pragma unroll
        for (int i = 0; i < NT / 64; ++i) s += red[i];
        const int lin = blockIdx.x + (int)gridDim.x * (blockIdx.y + (int)gridDim.y * blockIdx.z);
        slots[lin] = s;
    }
}

__global__ __launch_bounds__(256) void ssim_finalize_kernel(
    const float* __restrict__ slots, float* __restrict__ out, float invTwoN)
{
    __shared__ float red[256 / 64];
    float s = 0.f;
    const float4* s4 = (const float4*)slots;
    for (int i = threadIdx.x; i < NBLK / 4; i += 256) {
        const float4 v = s4[i];
        s += (v.x + v.y) + (v.z + v.w);
    }
    s = wave_reduce(s);
    if ((threadIdx.x & 63) == 0) red[threadIdx.x >> 6] = s;
    __syncthreads();
    if (threadIdx.x == 0)
        out[0] = 1.f - (red[0] + red[1] + red[2] + red[3]) * invTwoN;
}

extern "C" void kernel_launch(void* const* d_in, const int* in_sizes, int n_in,
                              void* d_out, int out_size, void* d_ws, size_t ws_size,
                              hipStream_t stream) {
    const float* fused = (const float*)d_in[0];
    const float* img_a = (const float*)d_in[1];
    const float* img_b = (const float*)d_in[2];
    float* out = (float*)d_out;
    float* slots = (float*)d_ws;   // NBLK floats = 16 KB of scratch

    dim3 grid(IMW / TW, IMH / TH, 16);
    ssim_main_kernel<<<grid, NT, 0, stream>>>(fused, img_a, img_b, slots);

    const float invTwoN = 1.f / (2.f * 16.f * (float)IMW * (float)IMH);
    ssim_finalize_kernel<<<1, 256, 0, stream>>>(slots, out, invTwoN);
}